// Round 6
// baseline (293.727 us; speedup 1.0000x reference)
//
#include <hip/hip_runtime.h>
#include <hip/hip_bf16.h>
#include <math.h>

#define N_NODES 50000
#define N_EDGES 800000
#define DIM 96
#define HEADS 4
#define HEAD_DIM 24
#define SLOPE 0.2f
#define LN_EPS 1e-5f

#define GT 192        // threads for the two tiled GEMM kernels (3 waves)
#define TNODES 32     // nodes per tile
#define XPAD 100      // x/g tile row stride (400B: 16B-aligned, 4-way banks)
#define PWPAD 108     // PW tile row stride (432B: 16B-aligned, 3-way banks)

#define SCAN_BLK 512
#define SCAN_NB ((N_NODES + SCAN_BLK - 1) / SCAN_BLK)   // 98

__device__ __forceinline__ unsigned short f2bf(float f) {
    unsigned u = __float_as_uint(f);
    u += 0x7FFFu + ((u >> 16) & 1u);          // round-to-nearest-even
    return (unsigned short)(u >> 16);
}
__device__ __forceinline__ float bf2f(unsigned short v) {
    return __uint_as_float(((unsigned)v) << 16);
}

// ---------------------------------------------------------------------------
// Kernel A: h = x @ W, 4x4 register tile per thread, float4 LDS reads.
// h stored bf16 (aggregate-only consumer); attention dots from f32 regs.
// ---------------------------------------------------------------------------
__global__ __launch_bounds__(GT) void k_transform(
    const float* __restrict__ x, const float* __restrict__ W,
    const float* __restrict__ attS, const float* __restrict__ attD,
    unsigned short* __restrict__ hb, float* __restrict__ asrc,
    float* __restrict__ adst)
{
    __shared__ float Wl[DIM][DIM];        // [k][f] 36.9 KB
    __shared__ float xl[TNODES][XPAD];    // 12.5 KB (reused as h-tile)
    __shared__ float attl[2][DIM];
    const int tid = threadIdx.x;
    for (int i = tid; i < DIM * DIM; i += GT) Wl[i / DIM][i % DIM] = W[i];
    if (tid < DIM) { attl[0][tid] = attS[tid]; attl[1][tid] = attD[tid]; }
    const int tf = tid % 24, tn = tid / 24;     // 24 feat-groups x 8 node-groups
    const int f0 = tf * 4, n0 = tn * 4;
    const int ntiles = (N_NODES + TNODES - 1) / TNODES;

    for (int tile = blockIdx.x; tile < ntiles; tile += gridDim.x) {
        const int base = tile * TNODES;
        __syncthreads();   // Wl ready (iter 0); xl consumers done (iter>0)
        for (int i = tid; i < TNODES * DIM; i += GT) {
            const int n = i / DIM, f = i % DIM, gn = base + n;
            xl[n][f] = (gn < N_NODES) ? x[(size_t)gn * DIM + f] : 0.f;
        }
        __syncthreads();
        float acc[4][4] = {};
        for (int k = 0; k < DIM; k += 4) {
            float4 xq[4], wq[4];
            #pragma unroll
            for (int a = 0; a < 4; ++a) xq[a] = *(const float4*)&xl[n0 + a][k];
            #pragma unroll
            for (int j = 0; j < 4; ++j) wq[j] = *(const float4*)&Wl[k + j][f0];
            #pragma unroll
            for (int a = 0; a < 4; ++a) {
                const float x0 = xq[a].x, x1 = xq[a].y, x2 = xq[a].z, x3 = xq[a].w;
                acc[a][0] += x0 * wq[0].x + x1 * wq[1].x + x2 * wq[2].x + x3 * wq[3].x;
                acc[a][1] += x0 * wq[0].y + x1 * wq[1].y + x2 * wq[2].y + x3 * wq[3].y;
                acc[a][2] += x0 * wq[0].z + x1 * wq[1].z + x2 * wq[2].z + x3 * wq[3].z;
                acc[a][3] += x0 * wq[0].w + x1 * wq[1].w + x2 * wq[2].w + x3 * wq[3].w;
            }
        }
        #pragma unroll
        for (int a = 0; a < 4; ++a) {
            const int gn = base + n0 + a;
            if (gn < N_NODES) {
                ushort4 hv;
                hv.x = f2bf(acc[a][0]); hv.y = f2bf(acc[a][1]);
                hv.z = f2bf(acc[a][2]); hv.w = f2bf(acc[a][3]);
                *(ushort4*)&hb[(size_t)gn * DIM + f0] = hv;
            }
        }
        __syncthreads();   // all xl reads done -> reuse as h-tile (f32)
        #pragma unroll
        for (int a = 0; a < 4; ++a)
            *(float4*)&xl[n0 + a][f0] =
                make_float4(acc[a][0], acc[a][1], acc[a][2], acc[a][3]);
        __syncthreads();
        if (tid < TNODES * HEADS) {        // 128 threads: (node, head)
            const int l = tid >> 2, hd = tid & 3, gn = base + l;
            if (gn < N_NODES) {
                float s = 0.f, dd = 0.f;
                #pragma unroll
                for (int kk = 0; kk < HEAD_DIM; ++kk) {
                    const float hv = xl[l][hd * HEAD_DIM + kk];
                    s  += hv * attl[0][hd * HEAD_DIM + kk];
                    dd += hv * attl[1][hd * HEAD_DIM + kk];
                }
                asrc[gn * HEADS + hd] = s;
                adst[gn * HEADS + hd] = dd;
            }
        }
    }
}

// ---------------------------------------------------------------------------
// CSR build: histogram -> hierarchical scan -> scatter (+fused edge weights)
// ---------------------------------------------------------------------------
__global__ void k_hist(const int* __restrict__ ei, int* __restrict__ counts)
{
    const int e = blockIdx.x * 256 + threadIdx.x;
    if (e >= N_EDGES) return;
    const int d = ei[N_EDGES + e];
    if ((unsigned)d < N_NODES) atomicAdd(&counts[d], 1);
}

__global__ __launch_bounds__(SCAN_BLK) void k_scan_partial(
    const int* __restrict__ counts, int* __restrict__ bsum)
{
    __shared__ int red[SCAN_BLK];
    const int t = threadIdx.x;
    const int i = blockIdx.x * SCAN_BLK + t;
    red[t] = (i < N_NODES) ? counts[i] : 0;
    __syncthreads();
    #pragma unroll
    for (int off = SCAN_BLK / 2; off > 0; off >>= 1) {
        if (t < off) red[t] += red[t + off];
        __syncthreads();
    }
    if (t == 0) bsum[blockIdx.x] = red[0];
}

__global__ __launch_bounds__(128) void k_scan_bsums(
    const int* __restrict__ bsum, int* __restrict__ bpre, int* __restrict__ offsets)
{
    __shared__ int s[128];
    const int t = threadIdx.x;
    const int v = (t < SCAN_NB) ? bsum[t] : 0;
    s[t] = v;
    __syncthreads();
    #pragma unroll
    for (int off = 1; off < 128; off <<= 1) {
        const int u = (t >= off) ? s[t - off] : 0;
        __syncthreads();
        s[t] += u;
        __syncthreads();
    }
    if (t < SCAN_NB) bpre[t] = s[t] - v;
    if (t == 127) offsets[N_NODES] = s[127];      // total valid edges
}

__global__ __launch_bounds__(SCAN_BLK) void k_scan_final(
    const int* __restrict__ counts, const int* __restrict__ bpre,
    int* __restrict__ offsets, int* __restrict__ cursor)
{
    __shared__ int s[SCAN_BLK];
    const int t = threadIdx.x;
    const int i = blockIdx.x * SCAN_BLK + t;
    const int v = (i < N_NODES) ? counts[i] : 0;
    s[t] = v;
    __syncthreads();
    #pragma unroll
    for (int off = 1; off < SCAN_BLK; off <<= 1) {
        const int u = (t >= off) ? s[t - off] : 0;
        __syncthreads();
        s[t] += u;
        __syncthreads();
    }
    if (i < N_NODES) {
        const int ex = bpre[blockIdx.x] + s[t] - v;
        offsets[i] = ex;
        cursor[i] = ex;
    }
}

// scatter src ids into dst-sorted order AND compute per-edge weights inline
__global__ void k_scatter_w(const int* __restrict__ ei, int* __restrict__ cursor,
                            const float* __restrict__ asrc, const float* __restrict__ adst,
                            int* __restrict__ ssrc, float* __restrict__ wsrt)
{
    const int e = blockIdx.x * 256 + threadIdx.x;
    if (e >= N_EDGES) return;
    const int s = ei[e], d = ei[N_EDGES + e];
    if ((unsigned)s >= N_NODES || (unsigned)d >= N_NODES) return;
    const int pos = atomicAdd(&cursor[d], 1);
    ssrc[pos] = s;
    const float4 as = *(const float4*)&asrc[s * 4];
    const float4 ad = *(const float4*)&adst[d * 4];
    float l; float4 w;
    l = as.x + ad.x; l = (l > 0.f) ? l : SLOPE * l; w.x = __expf(l);
    l = as.y + ad.y; l = (l > 0.f) ? l : SLOPE * l; w.y = __expf(l);
    l = as.z + ad.z; l = (l > 0.f) ? l : SLOPE * l; w.z = __expf(l);
    l = as.w + ad.w; l = (l > 0.f) ? l : SLOPE * l; w.w = __expf(l);
    *(float4*)&wsrt[(size_t)pos * 4] = w;
}

// ---------------------------------------------------------------------------
// Kernel C: gather-aggregate. One wave per dst node; h gathered as bf16.
// ---------------------------------------------------------------------------
__global__ __launch_bounds__(256) void k_aggregate(
    const int* __restrict__ offsets, const int* __restrict__ ssrc,
    const float* __restrict__ wsrt,
    const unsigned short* __restrict__ hb, const float* __restrict__ asrc,
    const float* __restrict__ adst, const float* __restrict__ gb,
    float* __restrict__ out)
{
    const int wid  = (blockIdx.x * 256 + threadIdx.x) >> 6;
    const int lane = threadIdx.x & 63;
    if (wid >= N_NODES) return;
    const int d = wid;
    const bool has2 = (lane < 32);
    const int f0 = lane, f1 = 64 + lane;
    const int hd0 = f0 / HEAD_DIM;
    const int hd1 = has2 ? f1 / HEAD_DIM : 0;

    const int rs = offsets[d], re = offsets[d + 1];
    const int deg = re - rs;
    const int sv = (lane < deg) ? ssrc[rs + lane] : 0;   // coalesced preload
    const int cnt = deg + 1;                             // +1: self-loop (i==0)

    float acc0 = 0.f, acc1 = 0.f, ds0 = 0.f, ds1 = 0.f;

    // pipeline stage A = iteration 0 (self-loop; weight computed inline)
    float h0A = bf2f(hb[(size_t)d * DIM + f0]);
    float h1A = has2 ? bf2f(hb[(size_t)d * DIM + f1]) : 0.f;
    float l0 = asrc[d * HEADS + hd0] + adst[d * HEADS + hd0];
    l0 = (l0 > 0.f) ? l0 : SLOPE * l0;
    float w0A = __expf(l0);
    float w1A = 0.f;
    if (has2) {
        float l1 = asrc[d * HEADS + hd1] + adst[d * HEADS + hd1];
        l1 = (l1 > 0.f) ? l1 : SLOPE * l1;
        w1A = __expf(l1);
    }

    for (int i = 0; i < cnt; ++i) {
        float h0B = 0.f, h1B = 0.f, w0B = 0.f, w1B = 0.f;
        if (i + 1 < cnt) {
            const int j = i;                             // edge for iter i+1
            const int sB = (j < 64) ? __shfl(sv, j) : ssrc[rs + j];
            h0B = bf2f(hb[(size_t)sB * DIM + f0]);
            h1B = has2 ? bf2f(hb[(size_t)sB * DIM + f1]) : 0.f;
            const float* wp = wsrt + (size_t)(rs + j) * 4;
            w0B = wp[hd0];                               // same 16B line, broadcast
            w1B = has2 ? wp[hd1] : 0.f;
        }
        acc0 += w0A * h0A; ds0 += w0A;
        if (has2) { acc1 += w1A * h1A; ds1 += w1A; }
        h0A = h0B; h1A = h1B; w0A = w0B; w1A = w1B;
    }

    out[(size_t)d * DIM + f0] = acc0 / ds0 + gb[f0];
    if (has2) out[(size_t)d * DIM + f1] = acc1 / ds1 + gb[f1];
}

// ---------------------------------------------------------------------------
// Kernel D: proj (g @ PW^T + pb) 4x4-tiled, + residual + LayerNorm, in-place.
// ---------------------------------------------------------------------------
__global__ __launch_bounds__(GT) void k_finalize(
    const float* __restrict__ x, const float* __restrict__ PW,
    const float* __restrict__ pb, const float* __restrict__ lng,
    const float* __restrict__ lnb, float* __restrict__ out)
{
    __shared__ float PWl[DIM][PWPAD];     // [f][k] padded: 41.5 KB
    __shared__ float gl[TNODES][XPAD];    // 12.5 KB (g tile, reused as z tile)
    __shared__ float sred[TNODES][6], s2red[TNODES][6];
    __shared__ float mubuf[TNODES], ivbuf[TNODES];
    __shared__ float lngl[DIM], lnbl[DIM];
    const int tid = threadIdx.x;
    for (int i = tid; i < DIM * DIM; i += GT) PWl[i / DIM][i % DIM] = PW[i];
    if (tid < DIM) { lngl[tid] = lng[tid]; lnbl[tid] = lnb[tid]; }
    const int tf = tid % 24, tn = tid / 24;
    const int f0 = tf * 4, n0 = tn * 4;
    const float4 pbq = *(const float4*)&pb[f0];
    const int ntiles = (N_NODES + TNODES - 1) / TNODES;

    for (int tile = blockIdx.x; tile < ntiles; tile += gridDim.x) {
        const int base = tile * TNODES;
        __syncthreads();
        for (int i = tid; i < TNODES * DIM; i += GT) {
            const int n = i / DIM, f = i % DIM, gn = base + n;
            gl[n][f] = (gn < N_NODES) ? out[(size_t)gn * DIM + f] : 0.f;
        }
        __syncthreads();
        float acc[4][4] = {};
        for (int k = 0; k < DIM; k += 4) {
            float4 gq[4], wq[4];
            #pragma unroll
            for (int a = 0; a < 4; ++a) gq[a] = *(const float4*)&gl[n0 + a][k];
            #pragma unroll
            for (int b = 0; b < 4; ++b) wq[b] = *(const float4*)&PWl[f0 + b][k];
            #pragma unroll
            for (int a = 0; a < 4; ++a) {
                acc[a][0] += gq[a].x*wq[0].x + gq[a].y*wq[0].y + gq[a].z*wq[0].z + gq[a].w*wq[0].w;
                acc[a][1] += gq[a].x*wq[1].x + gq[a].y*wq[1].y + gq[a].z*wq[1].z + gq[a].w*wq[1].w;
                acc[a][2] += gq[a].x*wq[2].x + gq[a].y*wq[2].y + gq[a].z*wq[2].z + gq[a].w*wq[2].w;
                acc[a][3] += gq[a].x*wq[3].x + gq[a].y*wq[3].y + gq[a].z*wq[3].z + gq[a].w*wq[3].w;
            }
        }
        // z = x + pb + proj
        float4 zq[4];
        #pragma unroll
        for (int a = 0; a < 4; ++a) {
            const int gn = base + n0 + a;
            float4 xq = make_float4(0.f, 0.f, 0.f, 0.f);
            if (gn < N_NODES) xq = *(const float4*)&x[(size_t)gn * DIM + f0];
            zq[a] = make_float4(acc[a][0] + pbq.x + xq.x, acc[a][1] + pbq.y + xq.y,
                                acc[a][2] + pbq.z + xq.z, acc[a][3] + pbq.w + xq.w);
        }
        __syncthreads();   // gl (g) reads done -> reuse as z tile
        #pragma unroll
        for (int a = 0; a < 4; ++a) *(float4*)&gl[n0 + a][f0] = zq[a];
        __syncthreads();
        {   // partial sums: 6 threads per node, 16 elems each
            const int n = tid / 6, j = tid % 6;
            float s = 0.f, s2 = 0.f;
            #pragma unroll
            for (int c = 0; c < 16; ++c) {
                const float v = gl[n][j * 16 + c];
                s += v; s2 += v * v;
            }
            sred[n][j] = s; s2red[n][j] = s2;
        }
        __syncthreads();
        if (tid < TNODES) {
            float s = 0.f, s2 = 0.f;
            #pragma unroll
            for (int j = 0; j < 6; ++j) { s += sred[tid][j]; s2 += s2red[tid][j]; }
            const float mu = s * (1.f / DIM);
            const float var = s2 * (1.f / DIM) - mu * mu;
            mubuf[tid] = mu;
            ivbuf[tid] = rsqrtf(var + LN_EPS);
        }
        __syncthreads();
        for (int i = tid; i < TNODES * 24; i += GT) {
            const int n = i / 24, c = i % 24, gn = base + n;
            if (gn < N_NODES) {
                const float4 v = *(const float4*)&gl[n][c * 4];
                const float mu = mubuf[n], iv = ivbuf[n];
                float4 o;
                o.x = lngl[c*4+0] * (v.x - mu) * iv + lnbl[c*4+0];
                o.y = lngl[c*4+1] * (v.y - mu) * iv + lnbl[c*4+1];
                o.z = lngl[c*4+2] * (v.z - mu) * iv + lnbl[c*4+2];
                o.w = lngl[c*4+3] * (v.w - mu) * iv + lnbl[c*4+3];
                *(float4*)&out[(size_t)gn * DIM + c * 4] = o;
            }
        }
    }
}

// ---------------------------------------------------------------------------
extern "C" void kernel_launch(void* const* d_in, const int* in_sizes, int n_in,
                              void* d_out, int out_size, void* d_ws, size_t ws_size,
                              hipStream_t stream)
{
    const float* x    = (const float*)d_in[0];
    const int*   ei   = (const int*)d_in[1];     // [2, E] int32 (harness-converted)
    const float* W    = (const float*)d_in[2];
    const float* attS = (const float*)d_in[3];
    const float* attD = (const float*)d_in[4];
    const float* gb   = (const float*)d_in[5];
    const float* PW   = (const float*)d_in[6];
    const float* pb   = (const float*)d_in[7];
    const float* lng  = (const float*)d_in[8];
    const float* lnb  = (const float*)d_in[9];
    float* out = (float*)d_out;

    char* ws = (char*)d_ws;
    float* wsrt    = (float*)ws;                                  // E*4 f32 (12.8 MB)
    float* asrc    = wsrt + (size_t)N_EDGES * 4;                  // N*4 (16B-aligned)
    float* adst    = asrc + N_NODES * HEADS;                      // N*4
    unsigned short* hb = (unsigned short*)(adst + N_NODES * HEADS); // N*96 bf16 (9.6 MB)
    int*   counts  = (int*)(hb + (size_t)N_NODES * DIM);          // N
    int*   offsets = counts + N_NODES;                            // N+1
    int*   cursor  = offsets + N_NODES + 1;                       // N
    int*   bsum    = cursor + N_NODES;                            // SCAN_NB
    int*   bpre    = bsum + SCAN_NB;                              // SCAN_NB
    int*   ssrc    = bpre + SCAN_NB;                              // E

    hipMemsetAsync(counts, 0, N_NODES * sizeof(int), stream);
    k_hist        <<<(N_EDGES + 255) / 256, 256, 0, stream>>>(ei, counts);
    k_scan_partial<<<SCAN_NB, SCAN_BLK, 0, stream>>>(counts, bsum);
    k_scan_bsums  <<<1, 128, 0, stream>>>(bsum, bpre, offsets);
    k_scan_final  <<<SCAN_NB, SCAN_BLK, 0, stream>>>(counts, bpre, offsets, cursor);
    k_transform   <<<784, GT, 0, stream>>>(x, W, attS, attD, hb, asrc, adst);
    k_scatter_w   <<<(N_EDGES + 255) / 256, 256, 0, stream>>>(ei, cursor, asrc, adst, ssrc, wsrt);
    k_aggregate   <<<(N_NODES * 64 + 255) / 256, 256, 0, stream>>>(offsets, ssrc, wsrt, hb, asrc, adst, gb, out);
    k_finalize    <<<784, GT, 0, stream>>>(x, PW, pb, lng, lnb, out);
}

// Round 7
// 245.790 us; speedup vs baseline: 1.1950x; 1.1950x over previous
//
#include <hip/hip_runtime.h>
#include <hip/hip_bf16.h>
#include <math.h>

#define N_NODES 50000
#define N_EDGES 800000
#define DIM 96
#define HEADS 4
#define HEAD_DIM 24
#define SLOPE 0.2f
#define LN_EPS 1e-5f

#define GT 192        // threads for the two tiled GEMM kernels (3 waves)
#define TNODES 32     // nodes per tile
#define XPAD 100      // x/g tile row stride (400B: 16B-aligned, 4-way banks)
#define PWPAD 108     // PW tile row stride (432B: 16B-aligned, 3-way banks)

#define SCAN_BLK 512
#define SCAN_NB ((N_NODES + SCAN_BLK - 1) / SCAN_BLK)   // 98

__device__ __forceinline__ unsigned short f2bf(float f) {
    unsigned u = __float_as_uint(f);
    u += 0x7FFFu + ((u >> 16) & 1u);          // round-to-nearest-even
    return (unsigned short)(u >> 16);
}
__device__ __forceinline__ float bf2f(unsigned short v) {
    return __uint_as_float(((unsigned)v) << 16);
}

// ---------------------------------------------------------------------------
// Kernel A: h = x @ W, 4x4 register tile per thread, float4 LDS reads.
// h stored bf16 (aggregate-only consumer); attention dots from f32 regs.
// ---------------------------------------------------------------------------
__global__ __launch_bounds__(GT) void k_transform(
    const float* __restrict__ x, const float* __restrict__ W,
    const float* __restrict__ attS, const float* __restrict__ attD,
    unsigned short* __restrict__ hb, float* __restrict__ asrc,
    float* __restrict__ adst)
{
    __shared__ float Wl[DIM][DIM];        // [k][f] 36.9 KB
    __shared__ float xl[TNODES][XPAD];    // 12.5 KB (reused as h-tile)
    __shared__ float attl[2][DIM];
    const int tid = threadIdx.x;
    for (int i = tid; i < DIM * DIM; i += GT) Wl[i / DIM][i % DIM] = W[i];
    if (tid < DIM) { attl[0][tid] = attS[tid]; attl[1][tid] = attD[tid]; }
    const int tf = tid % 24, tn = tid / 24;     // 24 feat-groups x 8 node-groups
    const int f0 = tf * 4, n0 = tn * 4;
    const int ntiles = (N_NODES + TNODES - 1) / TNODES;

    for (int tile = blockIdx.x; tile < ntiles; tile += gridDim.x) {
        const int base = tile * TNODES;
        __syncthreads();   // Wl ready (iter 0); xl consumers done (iter>0)
        for (int i = tid; i < TNODES * DIM; i += GT) {
            const int n = i / DIM, f = i % DIM, gn = base + n;
            xl[n][f] = (gn < N_NODES) ? x[(size_t)gn * DIM + f] : 0.f;
        }
        __syncthreads();
        float acc[4][4] = {};
        for (int k = 0; k < DIM; k += 4) {
            float4 xq[4], wq[4];
            #pragma unroll
            for (int a = 0; a < 4; ++a) xq[a] = *(const float4*)&xl[n0 + a][k];
            #pragma unroll
            for (int j = 0; j < 4; ++j) wq[j] = *(const float4*)&Wl[k + j][f0];
            #pragma unroll
            for (int a = 0; a < 4; ++a) {
                const float x0 = xq[a].x, x1 = xq[a].y, x2 = xq[a].z, x3 = xq[a].w;
                acc[a][0] += x0 * wq[0].x + x1 * wq[1].x + x2 * wq[2].x + x3 * wq[3].x;
                acc[a][1] += x0 * wq[0].y + x1 * wq[1].y + x2 * wq[2].y + x3 * wq[3].y;
                acc[a][2] += x0 * wq[0].z + x1 * wq[1].z + x2 * wq[2].z + x3 * wq[3].z;
                acc[a][3] += x0 * wq[0].w + x1 * wq[1].w + x2 * wq[2].w + x3 * wq[3].w;
            }
        }
        #pragma unroll
        for (int a = 0; a < 4; ++a) {
            const int gn = base + n0 + a;
            if (gn < N_NODES) {
                ushort4 hv;
                hv.x = f2bf(acc[a][0]); hv.y = f2bf(acc[a][1]);
                hv.z = f2bf(acc[a][2]); hv.w = f2bf(acc[a][3]);
                *(ushort4*)&hb[(size_t)gn * DIM + f0] = hv;
            }
        }
        __syncthreads();   // all xl reads done -> reuse as h-tile (f32)
        #pragma unroll
        for (int a = 0; a < 4; ++a)
            *(float4*)&xl[n0 + a][f0] =
                make_float4(acc[a][0], acc[a][1], acc[a][2], acc[a][3]);
        __syncthreads();
        if (tid < TNODES * HEADS) {        // 128 threads: (node, head)
            const int l = tid >> 2, hd = tid & 3, gn = base + l;
            if (gn < N_NODES) {
                float s = 0.f, dd = 0.f;
                #pragma unroll
                for (int kk = 0; kk < HEAD_DIM; ++kk) {
                    const float hv = xl[l][hd * HEAD_DIM + kk];
                    s  += hv * attl[0][hd * HEAD_DIM + kk];
                    dd += hv * attl[1][hd * HEAD_DIM + kk];
                }
                asrc[gn * HEADS + hd] = s;
                adst[gn * HEADS + hd] = dd;
            }
        }
    }
}

// ---------------------------------------------------------------------------
// CSR build: histogram -> hierarchical scan -> scatter (+fused edge weights)
// ---------------------------------------------------------------------------
__global__ void k_hist(const int* __restrict__ ei, int* __restrict__ counts)
{
    const int e = blockIdx.x * 256 + threadIdx.x;
    if (e >= N_EDGES) return;
    const int d = ei[N_EDGES + e];
    if ((unsigned)d < N_NODES) atomicAdd(&counts[d], 1);
}

__global__ __launch_bounds__(SCAN_BLK) void k_scan_partial(
    const int* __restrict__ counts, int* __restrict__ bsum)
{
    __shared__ int red[SCAN_BLK];
    const int t = threadIdx.x;
    const int i = blockIdx.x * SCAN_BLK + t;
    red[t] = (i < N_NODES) ? counts[i] : 0;
    __syncthreads();
    #pragma unroll
    for (int off = SCAN_BLK / 2; off > 0; off >>= 1) {
        if (t < off) red[t] += red[t + off];
        __syncthreads();
    }
    if (t == 0) bsum[blockIdx.x] = red[0];
}

__global__ __launch_bounds__(128) void k_scan_bsums(
    const int* __restrict__ bsum, int* __restrict__ bpre, int* __restrict__ offsets)
{
    __shared__ int s[128];
    const int t = threadIdx.x;
    const int v = (t < SCAN_NB) ? bsum[t] : 0;
    s[t] = v;
    __syncthreads();
    #pragma unroll
    for (int off = 1; off < 128; off <<= 1) {
        const int u = (t >= off) ? s[t - off] : 0;
        __syncthreads();
        s[t] += u;
        __syncthreads();
    }
    if (t < SCAN_NB) bpre[t] = s[t] - v;
    if (t == 127) offsets[N_NODES] = s[127];      // total valid edges
}

__global__ __launch_bounds__(SCAN_BLK) void k_scan_final(
    const int* __restrict__ counts, const int* __restrict__ bpre,
    int* __restrict__ offsets, int* __restrict__ cursor)
{
    __shared__ int s[SCAN_BLK];
    const int t = threadIdx.x;
    const int i = blockIdx.x * SCAN_BLK + t;
    const int v = (i < N_NODES) ? counts[i] : 0;
    s[t] = v;
    __syncthreads();
    #pragma unroll
    for (int off = 1; off < SCAN_BLK; off <<= 1) {
        const int u = (t >= off) ? s[t - off] : 0;
        __syncthreads();
        s[t] += u;
        __syncthreads();
    }
    if (i < N_NODES) {
        const int ex = bpre[blockIdx.x] + s[t] - v;
        offsets[i] = ex;
        cursor[i] = ex;
    }
}

// scatter src ids into dst-sorted order AND compute per-edge weights inline
__global__ void k_scatter_w(const int* __restrict__ ei, int* __restrict__ cursor,
                            const float* __restrict__ asrc, const float* __restrict__ adst,
                            int* __restrict__ ssrc, float* __restrict__ wsrt)
{
    const int e = blockIdx.x * 256 + threadIdx.x;
    if (e >= N_EDGES) return;
    const int s = ei[e], d = ei[N_EDGES + e];
    if ((unsigned)s >= N_NODES || (unsigned)d >= N_NODES) return;
    const int pos = atomicAdd(&cursor[d], 1);
    ssrc[pos] = s;
    const float4 as = *(const float4*)&asrc[s * 4];
    const float4 ad = *(const float4*)&adst[d * 4];
    float l; float4 w;
    l = as.x + ad.x; l = (l > 0.f) ? l : SLOPE * l; w.x = __expf(l);
    l = as.y + ad.y; l = (l > 0.f) ? l : SLOPE * l; w.y = __expf(l);
    l = as.z + ad.z; l = (l > 0.f) ? l : SLOPE * l; w.z = __expf(l);
    l = as.w + ad.w; l = (l > 0.f) ? l : SLOPE * l; w.w = __expf(l);
    *(float4*)&wsrt[(size_t)pos * 4] = w;
}

// ---------------------------------------------------------------------------
// Kernel C: gather-aggregate, 4-deep software pipeline.
// One wave per dst node. Lane l<48 owns feature pair (2l, 2l+1) -> the wave
// reads a full 192-B bf16 row in ONE dword gather. deg is wave-uniform.
// ---------------------------------------------------------------------------
__global__ __launch_bounds__(256) void k_aggregate(
    const int* __restrict__ offsets, const int* __restrict__ ssrc,
    const float* __restrict__ wsrt,
    const unsigned short* __restrict__ hb, const float* __restrict__ asrc,
    const float* __restrict__ adst, const float* __restrict__ gb,
    float* __restrict__ out)
{
    const int wid  = (blockIdx.x * 256 + threadIdx.x) >> 6;
    const int lane = threadIdx.x & 63;
    if (wid >= N_NODES) return;
    const int d = wid;
    const int lp = (lane < 48) ? lane : 47;     // lanes 48-63 duplicate lane 47
    const int f0 = lp * 2;                      // features f0, f0+1 (same head)
    const int hd = f0 / HEAD_DIM;

    const int rs = offsets[d], re = offsets[d + 1];
    const int deg = re - rs;
    const int sv = (lane < deg) ? ssrc[rs + lane] : 0;   // coalesced preload

    float acc0, acc1, ds;
    {   // self-loop term
        const unsigned int hp = *(const unsigned int*)&hb[(size_t)d * DIM + f0];
        float l0 = asrc[d * HEADS + hd] + adst[d * HEADS + hd];
        l0 = (l0 > 0.f) ? l0 : SLOPE * l0;
        const float w = __expf(l0);
        acc0 = w * bf2f((unsigned short)(hp & 0xffffu));
        acc1 = w * bf2f((unsigned short)(hp >> 16));
        ds = w;
    }

#define SRCJ(j) (((j) < 64) ? __shfl(sv, (j)) : ssrc[rs + (j)])
#define ISSUE(hreg, wreg, j) do { \
        const int s_ = SRCJ(j); \
        hreg = *(const unsigned int*)&hb[(size_t)s_ * DIM + f0]; \
        wreg = wsrt[(size_t)(rs + (j)) * 4 + hd]; } while (0)
#define CONSUME(hreg, wreg) do { \
        acc0 += (wreg) * bf2f((unsigned short)((hreg) & 0xffffu)); \
        acc1 += (wreg) * bf2f((unsigned short)((hreg) >> 16)); \
        ds += (wreg); } while (0)

    int j = 0;
    if (deg >= 4) {
        unsigned int h0, h1, h2, h3; float w0, w1, w2, w3;
        ISSUE(h0, w0, 0); ISSUE(h1, w1, 1); ISSUE(h2, w2, 2); ISSUE(h3, w3, 3);
        for (; j + 8 <= deg; j += 4) {
            CONSUME(h0, w0); ISSUE(h0, w0, j + 4);
            CONSUME(h1, w1); ISSUE(h1, w1, j + 5);
            CONSUME(h2, w2); ISSUE(h2, w2, j + 6);
            CONSUME(h3, w3); ISSUE(h3, w3, j + 7);
        }
        CONSUME(h0, w0); CONSUME(h1, w1); CONSUME(h2, w2); CONSUME(h3, w3);
        j += 4;
    }
    for (; j < deg; ++j) {
        unsigned int hh; float ww;
        ISSUE(hh, ww, j); CONSUME(hh, ww);
    }
#undef SRCJ
#undef ISSUE
#undef CONSUME

    if (lane < 48) {
        const float inv = 1.f / ds;             // ds > 0 (self-loop)
        float2 o;
        o.x = acc0 * inv + gb[f0];
        o.y = acc1 * inv + gb[f0 + 1];
        *(float2*)&out[(size_t)d * DIM + f0] = o;
    }
}

// ---------------------------------------------------------------------------
// Kernel D: proj (g @ PW^T + pb) 4x4-tiled, + residual + LayerNorm, in-place.
// ---------------------------------------------------------------------------
__global__ __launch_bounds__(GT) void k_finalize(
    const float* __restrict__ x, const float* __restrict__ PW,
    const float* __restrict__ pb, const float* __restrict__ lng,
    const float* __restrict__ lnb, float* __restrict__ out)
{
    __shared__ float PWl[DIM][PWPAD];     // [f][k] padded: 41.5 KB
    __shared__ float gl[TNODES][XPAD];    // 12.5 KB (g tile, reused as z tile)
    __shared__ float sred[TNODES][6], s2red[TNODES][6];
    __shared__ float mubuf[TNODES], ivbuf[TNODES];
    __shared__ float lngl[DIM], lnbl[DIM];
    const int tid = threadIdx.x;
    for (int i = tid; i < DIM * DIM; i += GT) PWl[i / DIM][i % DIM] = PW[i];
    if (tid < DIM) { lngl[tid] = lng[tid]; lnbl[tid] = lnb[tid]; }
    const int tf = tid % 24, tn = tid / 24;
    const int f0 = tf * 4, n0 = tn * 4;
    const float4 pbq = *(const float4*)&pb[f0];
    const int ntiles = (N_NODES + TNODES - 1) / TNODES;

    for (int tile = blockIdx.x; tile < ntiles; tile += gridDim.x) {
        const int base = tile * TNODES;
        __syncthreads();
        for (int i = tid; i < TNODES * DIM; i += GT) {
            const int n = i / DIM, f = i % DIM, gn = base + n;
            gl[n][f] = (gn < N_NODES) ? out[(size_t)gn * DIM + f] : 0.f;
        }
        __syncthreads();
        float acc[4][4] = {};
        for (int k = 0; k < DIM; k += 4) {
            float4 gq[4], wq[4];
            #pragma unroll
            for (int a = 0; a < 4; ++a) gq[a] = *(const float4*)&gl[n0 + a][k];
            #pragma unroll
            for (int b = 0; b < 4; ++b) wq[b] = *(const float4*)&PWl[f0 + b][k];
            #pragma unroll
            for (int a = 0; a < 4; ++a) {
                acc[a][0] += gq[a].x*wq[0].x + gq[a].y*wq[0].y + gq[a].z*wq[0].z + gq[a].w*wq[0].w;
                acc[a][1] += gq[a].x*wq[1].x + gq[a].y*wq[1].y + gq[a].z*wq[1].z + gq[a].w*wq[1].w;
                acc[a][2] += gq[a].x*wq[2].x + gq[a].y*wq[2].y + gq[a].z*wq[2].z + gq[a].w*wq[2].w;
                acc[a][3] += gq[a].x*wq[3].x + gq[a].y*wq[3].y + gq[a].z*wq[3].z + gq[a].w*wq[3].w;
            }
        }
        // z = x + pb + proj
        float4 zq[4];
        #pragma unroll
        for (int a = 0; a < 4; ++a) {
            const int gn = base + n0 + a;
            float4 xq = make_float4(0.f, 0.f, 0.f, 0.f);
            if (gn < N_NODES) xq = *(const float4*)&x[(size_t)gn * DIM + f0];
            zq[a] = make_float4(acc[a][0] + pbq.x + xq.x, acc[a][1] + pbq.y + xq.y,
                                acc[a][2] + pbq.z + xq.z, acc[a][3] + pbq.w + xq.w);
        }
        __syncthreads();   // gl (g) reads done -> reuse as z tile
        #pragma unroll
        for (int a = 0; a < 4; ++a) *(float4*)&gl[n0 + a][f0] = zq[a];
        __syncthreads();
        {   // partial sums: 6 threads per node, 16 elems each
            const int n = tid / 6, j = tid % 6;
            float s = 0.f, s2 = 0.f;
            #pragma unroll
            for (int c = 0; c < 16; ++c) {
                const float v = gl[n][j * 16 + c];
                s += v; s2 += v * v;
            }
            sred[n][j] = s; s2red[n][j] = s2;
        }
        __syncthreads();
        if (tid < TNODES) {
            float s = 0.f, s2 = 0.f;
            #pragma unroll
            for (int j = 0; j < 6; ++j) { s += sred[tid][j]; s2 += s2red[tid][j]; }
            const float mu = s * (1.f / DIM);
            const float var = s2 * (1.f / DIM) - mu * mu;
            mubuf[tid] = mu;
            ivbuf[tid] = rsqrtf(var + LN_EPS);
        }
        __syncthreads();
        for (int i = tid; i < TNODES * 24; i += GT) {
            const int n = i / 24, c = i % 24, gn = base + n;
            if (gn < N_NODES) {
                const float4 v = *(const float4*)&gl[n][c * 4];
                const float mu = mubuf[n], iv = ivbuf[n];
                float4 o;
                o.x = lngl[c*4+0] * (v.x - mu) * iv + lnbl[c*4+0];
                o.y = lngl[c*4+1] * (v.y - mu) * iv + lnbl[c*4+1];
                o.z = lngl[c*4+2] * (v.z - mu) * iv + lnbl[c*4+2];
                o.w = lngl[c*4+3] * (v.w - mu) * iv + lnbl[c*4+3];
                *(float4*)&out[(size_t)gn * DIM + c * 4] = o;
            }
        }
    }
}

// ---------------------------------------------------------------------------
extern "C" void kernel_launch(void* const* d_in, const int* in_sizes, int n_in,
                              void* d_out, int out_size, void* d_ws, size_t ws_size,
                              hipStream_t stream)
{
    const float* x    = (const float*)d_in[0];
    const int*   ei   = (const int*)d_in[1];     // [2, E] int32 (harness-converted)
    const float* W    = (const float*)d_in[2];
    const float* attS = (const float*)d_in[3];
    const float* attD = (const float*)d_in[4];
    const float* gb   = (const float*)d_in[5];
    const float* PW   = (const float*)d_in[6];
    const float* pb   = (const float*)d_in[7];
    const float* lng  = (const float*)d_in[8];
    const float* lnb  = (const float*)d_in[9];
    float* out = (float*)d_out;

    char* ws = (char*)d_ws;
    float* wsrt    = (float*)ws;                                  // E*4 f32 (12.8 MB)
    float* asrc    = wsrt + (size_t)N_EDGES * 4;                  // N*4 (16B-aligned)
    float* adst    = asrc + N_NODES * HEADS;                      // N*4
    unsigned short* hb = (unsigned short*)(adst + N_NODES * HEADS); // N*96 bf16 (9.6 MB)
    int*   counts  = (int*)(hb + (size_t)N_NODES * DIM);          // N
    int*   offsets = counts + N_NODES;                            // N+1
    int*   cursor  = offsets + N_NODES + 1;                       // N
    int*   bsum    = cursor + N_NODES;                            // SCAN_NB
    int*   bpre    = bsum + SCAN_NB;                              // SCAN_NB
    int*   ssrc    = bpre + SCAN_NB;                              // E

    hipMemsetAsync(counts, 0, N_NODES * sizeof(int), stream);
    k_hist        <<<(N_EDGES + 255) / 256, 256, 0, stream>>>(ei, counts);
    k_scan_partial<<<SCAN_NB, SCAN_BLK, 0, stream>>>(counts, bsum);
    k_scan_bsums  <<<1, 128, 0, stream>>>(bsum, bpre, offsets);
    k_scan_final  <<<SCAN_NB, SCAN_BLK, 0, stream>>>(counts, bpre, offsets, cursor);
    k_transform   <<<784, GT, 0, stream>>>(x, W, attS, attD, hb, asrc, adst);
    k_scatter_w   <<<(N_EDGES + 255) / 256, 256, 0, stream>>>(ei, cursor, asrc, adst, ssrc, wsrt);
    k_aggregate   <<<(N_NODES * 64 + 255) / 256, 256, 0, stream>>>(offsets, ssrc, wsrt, hb, asrc, adst, gb, out);
    k_finalize    <<<784, GT, 0, stream>>>(x, PW, pb, lng, lnb, out);
}

// Round 8
// 222.084 us; speedup vs baseline: 1.3226x; 1.1067x over previous
//
#include <hip/hip_runtime.h>
#include <hip/hip_bf16.h>
#include <math.h>

#define N_NODES 50000
#define N_EDGES 800000
#define DIM 96
#define HEADS 4
#define HEAD_DIM 24
#define SLOPE 0.2f
#define LN_EPS 1e-5f

#define GT 192        // 3 waves; 12 feat-groups (8 feats) x 16 node-groups (4 nodes)
#define TNODES 64     // nodes per tile
#define XPAD 100      // x/g tile row stride (400B: 16B-aligned)
#define NTILES ((N_NODES + TNODES - 1) / TNODES)   // 782

#define SCAN_BLK 512
#define SCAN_NB ((N_NODES + SCAN_BLK - 1) / SCAN_BLK)   // 98

__device__ __forceinline__ unsigned short f2bf(float f) {
    unsigned u = __float_as_uint(f);
    u += 0x7FFFu + ((u >> 16) & 1u);          // round-to-nearest-even
    return (unsigned short)(u >> 16);
}
__device__ __forceinline__ float bf2f(unsigned short v) {
    return __uint_as_float(((unsigned)v) << 16);
}
__device__ __forceinline__ unsigned pack2bf(float a, float b) {
    return (unsigned)f2bf(a) | ((unsigned)f2bf(b) << 16);
}

// ---------------------------------------------------------------------------
// Tiny one-time transpose: PWT[k][f] = PW[f][k]  (so finalize stages row-major)
// ---------------------------------------------------------------------------
__global__ void k_transpose_pw(const float* __restrict__ PW, float* __restrict__ PWT)
{
    const int i = blockIdx.x * 256 + threadIdx.x;
    if (i < DIM * DIM) PWT[i] = PW[(i % DIM) * DIM + i / DIM];
}

// ---------------------------------------------------------------------------
// Kernel A: h = x @ W, 4-node x 8-feat register tile, float4 LDS reads.
// h stored bf16; attention dots from f32 h-tile staged back to LDS.
// ---------------------------------------------------------------------------
__global__ __launch_bounds__(GT) void k_transform(
    const float* __restrict__ x, const float* __restrict__ W,
    const float* __restrict__ attS, const float* __restrict__ attD,
    unsigned short* __restrict__ hb, float* __restrict__ asrc,
    float* __restrict__ adst)
{
    __shared__ float Wl[DIM][DIM];        // [k][f] 36.9 KB
    __shared__ float xl[TNODES][XPAD];    // 25.6 KB (reused as h-tile)
    __shared__ float attl[2][DIM];
    const int tid = threadIdx.x;
    for (int i4 = tid; i4 < DIM * (DIM / 4); i4 += GT) {     // 12 iters, float4
        const int k = i4 / 24, q = i4 % 24;
        *(float4*)&Wl[k][q * 4] = *(const float4*)&W[k * DIM + q * 4];
    }
    if (tid < DIM) { attl[0][tid] = attS[tid]; attl[1][tid] = attD[tid]; }
    const int tf = tid % 12, tn = tid / 12;   // 12 feat-groups x 16 node-groups
    const int f0 = tf * 8, n0 = tn * 4;

    for (int tile = blockIdx.x; tile < NTILES; tile += gridDim.x) {
        const int base = tile * TNODES;
        __syncthreads();   // Wl ready (iter 0); xl consumers done (iter>0)
        for (int i4 = tid; i4 < TNODES * 24; i4 += GT) {     // 8 iters, float4
            const int n = i4 / 24, q = i4 % 24, gn = base + n;
            *(float4*)&xl[n][q * 4] = (gn < N_NODES)
                ? *(const float4*)&x[(size_t)gn * DIM + q * 4]
                : make_float4(0.f, 0.f, 0.f, 0.f);
        }
        __syncthreads();
        float acc[4][8] = {};
        for (int k = 0; k < DIM; k += 4) {
            float4 xq[4], wa[4], wb[4];
            #pragma unroll
            for (int a = 0; a < 4; ++a) xq[a] = *(const float4*)&xl[n0 + a][k];
            #pragma unroll
            for (int j = 0; j < 4; ++j) {
                wa[j] = *(const float4*)&Wl[k + j][f0];
                wb[j] = *(const float4*)&Wl[k + j][f0 + 4];
            }
            #pragma unroll
            for (int a = 0; a < 4; ++a) {
                const float x0 = xq[a].x, x1 = xq[a].y, x2 = xq[a].z, x3 = xq[a].w;
                acc[a][0] += x0*wa[0].x + x1*wa[1].x + x2*wa[2].x + x3*wa[3].x;
                acc[a][1] += x0*wa[0].y + x1*wa[1].y + x2*wa[2].y + x3*wa[3].y;
                acc[a][2] += x0*wa[0].z + x1*wa[1].z + x2*wa[2].z + x3*wa[3].z;
                acc[a][3] += x0*wa[0].w + x1*wa[1].w + x2*wa[2].w + x3*wa[3].w;
                acc[a][4] += x0*wb[0].x + x1*wb[1].x + x2*wb[2].x + x3*wb[3].x;
                acc[a][5] += x0*wb[0].y + x1*wb[1].y + x2*wb[2].y + x3*wb[3].y;
                acc[a][6] += x0*wb[0].z + x1*wb[1].z + x2*wb[2].z + x3*wb[3].z;
                acc[a][7] += x0*wb[0].w + x1*wb[1].w + x2*wb[2].w + x3*wb[3].w;
            }
        }
        #pragma unroll
        for (int a = 0; a < 4; ++a) {
            const int gn = base + n0 + a;
            if (gn < N_NODES) {
                uint4 hv;
                hv.x = pack2bf(acc[a][0], acc[a][1]);
                hv.y = pack2bf(acc[a][2], acc[a][3]);
                hv.z = pack2bf(acc[a][4], acc[a][5]);
                hv.w = pack2bf(acc[a][6], acc[a][7]);
                *(uint4*)&hb[(size_t)gn * DIM + f0] = hv;   // 8 bf16 = 16B
            }
        }
        __syncthreads();   // all xl reads done -> reuse as f32 h-tile
        #pragma unroll
        for (int a = 0; a < 4; ++a) {
            *(float4*)&xl[n0 + a][f0]     = make_float4(acc[a][0], acc[a][1], acc[a][2], acc[a][3]);
            *(float4*)&xl[n0 + a][f0 + 4] = make_float4(acc[a][4], acc[a][5], acc[a][6], acc[a][7]);
        }
        __syncthreads();
        for (int i = tid; i < TNODES * HEADS; i += GT) {     // (node, head) dots
            const int l = i >> 2, hd = i & 3, gn = base + l;
            if (gn < N_NODES) {
                float s = 0.f, dd = 0.f;
                #pragma unroll
                for (int kk = 0; kk < HEAD_DIM; ++kk) {
                    const float hv = xl[l][hd * HEAD_DIM + kk];
                    s  += hv * attl[0][hd * HEAD_DIM + kk];
                    dd += hv * attl[1][hd * HEAD_DIM + kk];
                }
                asrc[gn * HEADS + hd] = s;
                adst[gn * HEADS + hd] = dd;
            }
        }
    }
}

// ---------------------------------------------------------------------------
// CSR build: histogram -> hierarchical scan -> scatter (+fused edge weights)
// ---------------------------------------------------------------------------
__global__ void k_hist(const int* __restrict__ ei, int* __restrict__ counts)
{
    const int e = blockIdx.x * 256 + threadIdx.x;
    if (e >= N_EDGES) return;
    const int d = ei[N_EDGES + e];
    if ((unsigned)d < N_NODES) atomicAdd(&counts[d], 1);
}

__global__ __launch_bounds__(SCAN_BLK) void k_scan_partial(
    const int* __restrict__ counts, int* __restrict__ bsum)
{
    __shared__ int red[SCAN_BLK];
    const int t = threadIdx.x;
    const int i = blockIdx.x * SCAN_BLK + t;
    red[t] = (i < N_NODES) ? counts[i] : 0;
    __syncthreads();
    #pragma unroll
    for (int off = SCAN_BLK / 2; off > 0; off >>= 1) {
        if (t < off) red[t] += red[t + off];
        __syncthreads();
    }
    if (t == 0) bsum[blockIdx.x] = red[0];
}

__global__ __launch_bounds__(128) void k_scan_bsums(
    const int* __restrict__ bsum, int* __restrict__ bpre, int* __restrict__ offsets)
{
    __shared__ int s[128];
    const int t = threadIdx.x;
    const int v = (t < SCAN_NB) ? bsum[t] : 0;
    s[t] = v;
    __syncthreads();
    #pragma unroll
    for (int off = 1; off < 128; off <<= 1) {
        const int u = (t >= off) ? s[t - off] : 0;
        __syncthreads();
        s[t] += u;
        __syncthreads();
    }
    if (t < SCAN_NB) bpre[t] = s[t] - v;
    if (t == 127) offsets[N_NODES] = s[127];      // total valid edges
}

__global__ __launch_bounds__(SCAN_BLK) void k_scan_final(
    const int* __restrict__ counts, const int* __restrict__ bpre,
    int* __restrict__ offsets, int* __restrict__ cursor)
{
    __shared__ int s[SCAN_BLK];
    const int t = threadIdx.x;
    const int i = blockIdx.x * SCAN_BLK + t;
    const int v = (i < N_NODES) ? counts[i] : 0;
    s[t] = v;
    __syncthreads();
    #pragma unroll
    for (int off = 1; off < SCAN_BLK; off <<= 1) {
        const int u = (t >= off) ? s[t - off] : 0;
        __syncthreads();
        s[t] += u;
        __syncthreads();
    }
    if (i < N_NODES) {
        const int ex = bpre[blockIdx.x] + s[t] - v;
        offsets[i] = ex;
        cursor[i] = ex;
    }
}

// scatter src ids into dst-sorted order AND compute per-edge weights inline
__global__ void k_scatter_w(const int* __restrict__ ei, int* __restrict__ cursor,
                            const float* __restrict__ asrc, const float* __restrict__ adst,
                            int* __restrict__ ssrc, float* __restrict__ wsrt)
{
    const int e = blockIdx.x * 256 + threadIdx.x;
    if (e >= N_EDGES) return;
    const int s = ei[e], d = ei[N_EDGES + e];
    if ((unsigned)s >= N_NODES || (unsigned)d >= N_NODES) return;
    const int pos = atomicAdd(&cursor[d], 1);
    ssrc[pos] = s;
    const float4 as = *(const float4*)&asrc[s * 4];
    const float4 ad = *(const float4*)&adst[d * 4];
    float l; float4 w;
    l = as.x + ad.x; l = (l > 0.f) ? l : SLOPE * l; w.x = __expf(l);
    l = as.y + ad.y; l = (l > 0.f) ? l : SLOPE * l; w.y = __expf(l);
    l = as.z + ad.z; l = (l > 0.f) ? l : SLOPE * l; w.z = __expf(l);
    l = as.w + ad.w; l = (l > 0.f) ? l : SLOPE * l; w.w = __expf(l);
    *(float4*)&wsrt[(size_t)pos * 4] = w;
}

// ---------------------------------------------------------------------------
// Kernel C: gather-aggregate, 4-deep software pipeline.
// One wave per dst node; lane l<48 owns feature pair (2l, 2l+1).
// ---------------------------------------------------------------------------
__global__ __launch_bounds__(256) void k_aggregate(
    const int* __restrict__ offsets, const int* __restrict__ ssrc,
    const float* __restrict__ wsrt,
    const unsigned short* __restrict__ hb, const float* __restrict__ asrc,
    const float* __restrict__ adst, const float* __restrict__ gb,
    float* __restrict__ out)
{
    const int wid  = (blockIdx.x * 256 + threadIdx.x) >> 6;
    const int lane = threadIdx.x & 63;
    if (wid >= N_NODES) return;
    const int d = wid;
    const int lp = (lane < 48) ? lane : 47;     // lanes 48-63 duplicate lane 47
    const int f0 = lp * 2;                      // features f0, f0+1 (same head)
    const int hd = f0 / HEAD_DIM;

    const int rs = offsets[d], re = offsets[d + 1];
    const int deg = re - rs;
    const int sv = (lane < deg) ? ssrc[rs + lane] : 0;   // coalesced preload

    float acc0, acc1, ds;
    {   // self-loop term
        const unsigned int hp = *(const unsigned int*)&hb[(size_t)d * DIM + f0];
        float l0 = asrc[d * HEADS + hd] + adst[d * HEADS + hd];
        l0 = (l0 > 0.f) ? l0 : SLOPE * l0;
        const float w = __expf(l0);
        acc0 = w * bf2f((unsigned short)(hp & 0xffffu));
        acc1 = w * bf2f((unsigned short)(hp >> 16));
        ds = w;
    }

#define SRCJ(j) (((j) < 64) ? __shfl(sv, (j)) : ssrc[rs + (j)])
#define ISSUE(hreg, wreg, j) do { \
        const int s_ = SRCJ(j); \
        hreg = *(const unsigned int*)&hb[(size_t)s_ * DIM + f0]; \
        wreg = wsrt[(size_t)(rs + (j)) * 4 + hd]; } while (0)
#define CONSUME(hreg, wreg) do { \
        acc0 += (wreg) * bf2f((unsigned short)((hreg) & 0xffffu)); \
        acc1 += (wreg) * bf2f((unsigned short)((hreg) >> 16)); \
        ds += (wreg); } while (0)

    int j = 0;
    if (deg >= 4) {
        unsigned int h0, h1, h2, h3; float w0, w1, w2, w3;
        ISSUE(h0, w0, 0); ISSUE(h1, w1, 1); ISSUE(h2, w2, 2); ISSUE(h3, w3, 3);
        for (; j + 8 <= deg; j += 4) {
            CONSUME(h0, w0); ISSUE(h0, w0, j + 4);
            CONSUME(h1, w1); ISSUE(h1, w1, j + 5);
            CONSUME(h2, w2); ISSUE(h2, w2, j + 6);
            CONSUME(h3, w3); ISSUE(h3, w3, j + 7);
        }
        CONSUME(h0, w0); CONSUME(h1, w1); CONSUME(h2, w2); CONSUME(h3, w3);
        j += 4;
    }
    for (; j < deg; ++j) {
        unsigned int hh; float ww;
        ISSUE(hh, ww, j); CONSUME(hh, ww);
    }
#undef SRCJ
#undef ISSUE
#undef CONSUME

    if (lane < 48) {
        const float inv = 1.f / ds;             // ds > 0 (self-loop)
        float2 o;
        o.x = acc0 * inv + gb[f0];
        o.y = acc1 * inv + gb[f0 + 1];
        *(float2*)&out[(size_t)d * DIM + f0] = o;
    }
}

// ---------------------------------------------------------------------------
// Kernel D: proj = g @ PW^T via pre-transposed PWT (row-major [k][f]),
// 4-node x 8-feat register tile, + residual + LayerNorm, in-place on out.
// ---------------------------------------------------------------------------
__global__ __launch_bounds__(GT) void k_finalize(
    const float* __restrict__ x, const float* __restrict__ PWT,
    const float* __restrict__ pb, const float* __restrict__ lng,
    const float* __restrict__ lnb, float* __restrict__ out)
{
    __shared__ float Wl[DIM][DIM];        // PWT tile [k][f] 36.9 KB
    __shared__ float gl[TNODES][XPAD];    // 25.6 KB (g tile, reused as z tile)
    __shared__ float sred[TNODES][6], s2red[TNODES][6];
    __shared__ float mubuf[TNODES], ivbuf[TNODES];
    __shared__ float lngl[DIM], lnbl[DIM];
    const int tid = threadIdx.x;
    for (int i4 = tid; i4 < DIM * (DIM / 4); i4 += GT) {
        const int k = i4 / 24, q = i4 % 24;
        *(float4*)&Wl[k][q * 4] = *(const float4*)&PWT[k * DIM + q * 4];
    }
    if (tid < DIM) { lngl[tid] = lng[tid]; lnbl[tid] = lnb[tid]; }
    const int tf = tid % 12, tn = tid / 12;
    const int f0 = tf * 8, n0 = tn * 4;
    const float4 pba = *(const float4*)&pb[f0];
    const float4 pbb = *(const float4*)&pb[f0 + 4];

    for (int tile = blockIdx.x; tile < NTILES; tile += gridDim.x) {
        const int base = tile * TNODES;
        __syncthreads();
        for (int i4 = tid; i4 < TNODES * 24; i4 += GT) {
            const int n = i4 / 24, q = i4 % 24, gn = base + n;
            *(float4*)&gl[n][q * 4] = (gn < N_NODES)
                ? *(const float4*)&out[(size_t)gn * DIM + q * 4]
                : make_float4(0.f, 0.f, 0.f, 0.f);
        }
        __syncthreads();
        float acc[4][8] = {};
        for (int k = 0; k < DIM; k += 4) {
            float4 gq[4], wa[4], wb[4];
            #pragma unroll
            for (int a = 0; a < 4; ++a) gq[a] = *(const float4*)&gl[n0 + a][k];
            #pragma unroll
            for (int j = 0; j < 4; ++j) {
                wa[j] = *(const float4*)&Wl[k + j][f0];
                wb[j] = *(const float4*)&Wl[k + j][f0 + 4];
            }
            #pragma unroll
            for (int a = 0; a < 4; ++a) {
                const float g0 = gq[a].x, g1 = gq[a].y, g2 = gq[a].z, g3 = gq[a].w;
                acc[a][0] += g0*wa[0].x + g1*wa[1].x + g2*wa[2].x + g3*wa[3].x;
                acc[a][1] += g0*wa[0].y + g1*wa[1].y + g2*wa[2].y + g3*wa[3].y;
                acc[a][2] += g0*wa[0].z + g1*wa[1].z + g2*wa[2].z + g3*wa[3].z;
                acc[a][3] += g0*wa[0].w + g1*wa[1].w + g2*wa[2].w + g3*wa[3].w;
                acc[a][4] += g0*wb[0].x + g1*wb[1].x + g2*wb[2].x + g3*wb[3].x;
                acc[a][5] += g0*wb[0].y + g1*wb[1].y + g2*wb[2].y + g3*wb[3].y;
                acc[a][6] += g0*wb[0].z + g1*wb[1].z + g2*wb[2].z + g3*wb[3].z;
                acc[a][7] += g0*wb[0].w + g1*wb[1].w + g2*wb[2].w + g3*wb[3].w;
            }
        }
        // z = x + pb + proj (registers)
        float4 za[4], zb[4];
        #pragma unroll
        for (int a = 0; a < 4; ++a) {
            const int gn = base + n0 + a;
            float4 xa = make_float4(0.f,0.f,0.f,0.f), xb = xa;
            if (gn < N_NODES) {
                xa = *(const float4*)&x[(size_t)gn * DIM + f0];
                xb = *(const float4*)&x[(size_t)gn * DIM + f0 + 4];
            }
            za[a] = make_float4(acc[a][0]+pba.x+xa.x, acc[a][1]+pba.y+xa.y,
                                acc[a][2]+pba.z+xa.z, acc[a][3]+pba.w+xa.w);
            zb[a] = make_float4(acc[a][4]+pbb.x+xb.x, acc[a][5]+pbb.y+xb.y,
                                acc[a][6]+pbb.z+xb.z, acc[a][7]+pbb.w+xb.w);
        }
        __syncthreads();   // gl (g) reads done -> reuse as z tile
        #pragma unroll
        for (int a = 0; a < 4; ++a) {
            *(float4*)&gl[n0 + a][f0]     = za[a];
            *(float4*)&gl[n0 + a][f0 + 4] = zb[a];
        }
        __syncthreads();
        for (int i = tid; i < TNODES * 6; i += GT) {   // partials: 6/node x 16
            const int n = i / 6, jj = i % 6;
            float s = 0.f, s2 = 0.f;
            #pragma unroll
            for (int c = 0; c < 16; ++c) {
                const float v = gl[n][jj * 16 + c];
                s += v; s2 += v * v;
            }
            sred[n][jj] = s; s2red[n][jj] = s2;
        }
        __syncthreads();
        if (tid < TNODES) {
            float s = 0.f, s2 = 0.f;
            #pragma unroll
            for (int jj = 0; jj < 6; ++jj) { s += sred[tid][jj]; s2 += s2red[tid][jj]; }
            const float mu = s * (1.f / DIM);
            const float var = s2 * (1.f / DIM) - mu * mu;
            mubuf[tid] = mu;
            ivbuf[tid] = rsqrtf(var + LN_EPS);
        }
        __syncthreads();
        for (int i = tid; i < TNODES * 24; i += GT) {
            const int n = i / 24, c = i % 24, gn = base + n;
            if (gn < N_NODES) {
                const float4 v = *(const float4*)&gl[n][c * 4];
                const float mu = mubuf[n], iv = ivbuf[n];
                float4 o;
                o.x = lngl[c*4+0] * (v.x - mu) * iv + lnbl[c*4+0];
                o.y = lngl[c*4+1] * (v.y - mu) * iv + lnbl[c*4+1];
                o.z = lngl[c*4+2] * (v.z - mu) * iv + lnbl[c*4+2];
                o.w = lngl[c*4+3] * (v.w - mu) * iv + lnbl[c*4+3];
                *(float4*)&out[(size_t)gn * DIM + c * 4] = o;
            }
        }
    }
}

// ---------------------------------------------------------------------------
extern "C" void kernel_launch(void* const* d_in, const int* in_sizes, int n_in,
                              void* d_out, int out_size, void* d_ws, size_t ws_size,
                              hipStream_t stream)
{
    const float* x    = (const float*)d_in[0];
    const int*   ei   = (const int*)d_in[1];     // [2, E] int32 (harness-converted)
    const float* W    = (const float*)d_in[2];
    const float* attS = (const float*)d_in[3];
    const float* attD = (const float*)d_in[4];
    const float* gb   = (const float*)d_in[5];
    const float* PW   = (const float*)d_in[6];
    const float* pb   = (const float*)d_in[7];
    const float* lng  = (const float*)d_in[8];
    const float* lnb  = (const float*)d_in[9];
    float* out = (float*)d_out;

    char* ws = (char*)d_ws;
    float* wsrt    = (float*)ws;                                  // E*4 f32 (12.8 MB)
    float* asrc    = wsrt + (size_t)N_EDGES * 4;                  // N*4 (16B-aligned)
    float* adst    = asrc + N_NODES * HEADS;                      // N*4
    unsigned short* hb = (unsigned short*)(adst + N_NODES * HEADS); // N*96 bf16 (9.6 MB)
    float* pwt     = (float*)(hb + (size_t)N_NODES * DIM);        // 96*96 f32
    int*   counts  = (int*)(pwt + DIM * DIM);                     // N
    int*   offsets = counts + N_NODES;                            // N+1
    int*   cursor  = offsets + N_NODES + 1;                       // N
    int*   bsum    = cursor + N_NODES;                            // SCAN_NB
    int*   bpre    = bsum + SCAN_NB;                              // SCAN_NB
    int*   ssrc    = bpre + SCAN_NB;                              // E

    hipMemsetAsync(counts, 0, N_NODES * sizeof(int), stream);
    k_transpose_pw<<<(DIM * DIM + 255) / 256, 256, 0, stream>>>(PW, pwt);
    k_hist        <<<(N_EDGES + 255) / 256, 256, 0, stream>>>(ei, counts);
    k_scan_partial<<<SCAN_NB, SCAN_BLK, 0, stream>>>(counts, bsum);
    k_scan_bsums  <<<1, 128, 0, stream>>>(bsum, bpre, offsets);
    k_scan_final  <<<SCAN_NB, SCAN_BLK, 0, stream>>>(counts, bpre, offsets, cursor);
    k_transform   <<<NTILES, GT, 0, stream>>>(x, W, attS, attD, hb, asrc, adst);
    k_scatter_w   <<<(N_EDGES + 255) / 256, 256, 0, stream>>>(ei, cursor, asrc, adst, ssrc, wsrt);
    k_aggregate   <<<(N_NODES * 64 + 255) / 256, 256, 0, stream>>>(offsets, ssrc, wsrt, hb, asrc, adst, gb, out);
    k_finalize    <<<NTILES, GT, 0, stream>>>(x, pwt, pb, lng, lnb, out);
}

// Round 9
// 203.753 us; speedup vs baseline: 1.4416x; 1.0900x over previous
//
#include <hip/hip_runtime.h>
#include <hip/hip_bf16.h>
#include <math.h>

#define N_NODES 50000
#define N_EDGES 800000
#define DIM 96
#define HEADS 4
#define HEAD_DIM 24
#define SLOPE 0.2f
#define LN_EPS 1e-5f

#define GT 192        // 3 waves; 12 feat-groups (8 feats) x 16 node-groups (4 nodes)
#define TNODES 64     // nodes per tile
#define XPAD 100      // x/g tile row stride (400B: 16B-aligned)
#define NTILES ((N_NODES + TNODES - 1) / TNODES)   // 782

#define SCAN_BLK 512
#define SCAN_NB ((N_NODES + SCAN_BLK - 1) / SCAN_BLK)   // 98

__device__ __forceinline__ unsigned short f2bf(float f) {
    unsigned u = __float_as_uint(f);
    u += 0x7FFFu + ((u >> 16) & 1u);          // round-to-nearest-even
    return (unsigned short)(u >> 16);
}
__device__ __forceinline__ float bf2f(unsigned short v) {
    return __uint_as_float(((unsigned)v) << 16);
}
__device__ __forceinline__ unsigned pack2bf(float a, float b) {
    return (unsigned)f2bf(a) | ((unsigned)f2bf(b) << 16);
}

// ---------------------------------------------------------------------------
// Prep: zero counts + transpose PW (PWT[k][f] = PW[f][k]) in one dispatch.
// ---------------------------------------------------------------------------
__global__ void k_prep(const float* __restrict__ PW, float* __restrict__ pwt,
                       int* __restrict__ counts)
{
    const int i = blockIdx.x * 256 + threadIdx.x;
    if (i < N_NODES) counts[i] = 0;
    if (i < DIM * DIM) pwt[i] = PW[(i % DIM) * DIM + i / DIM];
}

// ---------------------------------------------------------------------------
// Kernel A: h = x @ W, 4-node x 8-feat register tile, float4 LDS reads.
// h stored bf16; attention dots from f32 h-tile staged back to LDS.
// ---------------------------------------------------------------------------
__global__ __launch_bounds__(GT) void k_transform(
    const float* __restrict__ x, const float* __restrict__ W,
    const float* __restrict__ attS, const float* __restrict__ attD,
    unsigned short* __restrict__ hb, float* __restrict__ asrc,
    float* __restrict__ adst)
{
    __shared__ float Wl[DIM][DIM];        // [k][f] 36.9 KB
    __shared__ float xl[TNODES][XPAD];    // 25.6 KB (reused as h-tile)
    __shared__ float attl[2][DIM];
    const int tid = threadIdx.x;
    for (int i4 = tid; i4 < DIM * (DIM / 4); i4 += GT) {     // float4 staging
        const int k = i4 / 24, q = i4 % 24;
        *(float4*)&Wl[k][q * 4] = *(const float4*)&W[k * DIM + q * 4];
    }
    if (tid < DIM) { attl[0][tid] = attS[tid]; attl[1][tid] = attD[tid]; }
    const int tf = tid % 12, tn = tid / 12;   // 12 feat-groups x 16 node-groups
    const int f0 = tf * 8, n0 = tn * 4;

    for (int tile = blockIdx.x; tile < NTILES; tile += gridDim.x) {
        const int base = tile * TNODES;
        __syncthreads();   // Wl ready (iter 0); xl consumers done (iter>0)
        for (int i4 = tid; i4 < TNODES * 24; i4 += GT) {
            const int n = i4 / 24, q = i4 % 24, gn = base + n;
            *(float4*)&xl[n][q * 4] = (gn < N_NODES)
                ? *(const float4*)&x[(size_t)gn * DIM + q * 4]
                : make_float4(0.f, 0.f, 0.f, 0.f);
        }
        __syncthreads();
        float acc[4][8] = {};
        for (int k = 0; k < DIM; k += 4) {
            float4 xq[4], wa[4], wb[4];
            #pragma unroll
            for (int a = 0; a < 4; ++a) xq[a] = *(const float4*)&xl[n0 + a][k];
            #pragma unroll
            for (int j = 0; j < 4; ++j) {
                wa[j] = *(const float4*)&Wl[k + j][f0];
                wb[j] = *(const float4*)&Wl[k + j][f0 + 4];
            }
            #pragma unroll
            for (int a = 0; a < 4; ++a) {
                const float x0 = xq[a].x, x1 = xq[a].y, x2 = xq[a].z, x3 = xq[a].w;
                acc[a][0] += x0*wa[0].x + x1*wa[1].x + x2*wa[2].x + x3*wa[3].x;
                acc[a][1] += x0*wa[0].y + x1*wa[1].y + x2*wa[2].y + x3*wa[3].y;
                acc[a][2] += x0*wa[0].z + x1*wa[1].z + x2*wa[2].z + x3*wa[3].z;
                acc[a][3] += x0*wa[0].w + x1*wa[1].w + x2*wa[2].w + x3*wa[3].w;
                acc[a][4] += x0*wb[0].x + x1*wb[1].x + x2*wb[2].x + x3*wb[3].x;
                acc[a][5] += x0*wb[0].y + x1*wb[1].y + x2*wb[2].y + x3*wb[3].y;
                acc[a][6] += x0*wb[0].z + x1*wb[1].z + x2*wb[2].z + x3*wb[3].z;
                acc[a][7] += x0*wb[0].w + x1*wb[1].w + x2*wb[2].w + x3*wb[3].w;
            }
        }
        #pragma unroll
        for (int a = 0; a < 4; ++a) {
            const int gn = base + n0 + a;
            if (gn < N_NODES) {
                uint4 hv;
                hv.x = pack2bf(acc[a][0], acc[a][1]);
                hv.y = pack2bf(acc[a][2], acc[a][3]);
                hv.z = pack2bf(acc[a][4], acc[a][5]);
                hv.w = pack2bf(acc[a][6], acc[a][7]);
                *(uint4*)&hb[(size_t)gn * DIM + f0] = hv;   // 8 bf16 = 16B
            }
        }
        __syncthreads();   // all xl reads done -> reuse as f32 h-tile
        #pragma unroll
        for (int a = 0; a < 4; ++a) {
            *(float4*)&xl[n0 + a][f0]     = make_float4(acc[a][0], acc[a][1], acc[a][2], acc[a][3]);
            *(float4*)&xl[n0 + a][f0 + 4] = make_float4(acc[a][4], acc[a][5], acc[a][6], acc[a][7]);
        }
        __syncthreads();
        for (int i = tid; i < TNODES * HEADS; i += GT) {     // (node, head) dots
            const int l = i >> 2, hd = i & 3, gn = base + l;
            if (gn < N_NODES) {
                float s = 0.f, dd = 0.f;
                #pragma unroll
                for (int kk = 0; kk < HEAD_DIM; ++kk) {
                    const float hv = xl[l][hd * HEAD_DIM + kk];
                    s  += hv * attl[0][hd * HEAD_DIM + kk];
                    dd += hv * attl[1][hd * HEAD_DIM + kk];
                }
                asrc[gn * HEADS + hd] = s;
                adst[gn * HEADS + hd] = dd;
            }
        }
    }
}

// ---------------------------------------------------------------------------
// CSR build: histogram -> partial sums -> (bsum-scan fused) final scan
// ---------------------------------------------------------------------------
__global__ void k_hist(const int* __restrict__ ei, int* __restrict__ counts)
{
    const int e = blockIdx.x * 256 + threadIdx.x;
    if (e >= N_EDGES) return;
    const int d = ei[N_EDGES + e];
    if ((unsigned)d < N_NODES) atomicAdd(&counts[d], 1);
}

__global__ __launch_bounds__(SCAN_BLK) void k_scan_partial(
    const int* __restrict__ counts, int* __restrict__ bsum)
{
    __shared__ int red[SCAN_BLK];
    const int t = threadIdx.x;
    const int i = blockIdx.x * SCAN_BLK + t;
    red[t] = (i < N_NODES) ? counts[i] : 0;
    __syncthreads();
    #pragma unroll
    for (int off = SCAN_BLK / 2; off > 0; off >>= 1) {
        if (t < off) red[t] += red[t + off];
        __syncthreads();
    }
    if (t == 0) bsum[blockIdx.x] = red[0];
}

__global__ __launch_bounds__(SCAN_BLK) void k_scan_final(
    const int* __restrict__ counts, const int* __restrict__ bsum,
    int* __restrict__ offsets, int* __restrict__ cursor)
{
    __shared__ int s[SCAN_BLK];
    __shared__ int bs[128];
    const int t = threadIdx.x;
    if (t < 128) bs[t] = (t < SCAN_NB) ? bsum[t] : 0;
    __syncthreads();
    #pragma unroll
    for (int off = 1; off < 128; off <<= 1) {       // inclusive scan of bsum
        int u = 0;
        if (t < 128 && t >= off) u = bs[t - off];
        __syncthreads();
        if (t < 128) bs[t] += u;
        __syncthreads();
    }
    const int i = blockIdx.x * SCAN_BLK + t;
    const int v = (i < N_NODES) ? counts[i] : 0;
    s[t] = v;
    __syncthreads();
    #pragma unroll
    for (int off = 1; off < SCAN_BLK; off <<= 1) {
        const int u = (t >= off) ? s[t - off] : 0;
        __syncthreads();
        s[t] += u;
        __syncthreads();
    }
    const int bpre = (blockIdx.x == 0) ? 0 : bs[blockIdx.x - 1];
    if (i < N_NODES) {
        const int ex = bpre + s[t] - v;
        offsets[i] = ex;
        cursor[i] = ex;
    }
    if (blockIdx.x == SCAN_NB - 1 && t == SCAN_BLK - 1)
        offsets[N_NODES] = bs[SCAN_NB - 1];         // total valid edges
}

// scatter src ids into dst-sorted order AND compute per-edge weights inline
__global__ void k_scatter_w(const int* __restrict__ ei, int* __restrict__ cursor,
                            const float* __restrict__ asrc, const float* __restrict__ adst,
                            int* __restrict__ ssrc, float* __restrict__ wsrt)
{
    const int e = blockIdx.x * 256 + threadIdx.x;
    if (e >= N_EDGES) return;
    const int s = ei[e], d = ei[N_EDGES + e];
    if ((unsigned)s >= N_NODES || (unsigned)d >= N_NODES) return;
    const int pos = atomicAdd(&cursor[d], 1);
    ssrc[pos] = s;
    const float4 as = *(const float4*)&asrc[s * 4];
    const float4 ad = *(const float4*)&adst[d * 4];
    float l; float4 w;
    l = as.x + ad.x; l = (l > 0.f) ? l : SLOPE * l; w.x = __expf(l);
    l = as.y + ad.y; l = (l > 0.f) ? l : SLOPE * l; w.y = __expf(l);
    l = as.z + ad.z; l = (l > 0.f) ? l : SLOPE * l; w.z = __expf(l);
    l = as.w + ad.w; l = (l > 0.f) ? l : SLOPE * l; w.w = __expf(l);
    *(float4*)&wsrt[(size_t)pos * 4] = w;
}

// ---------------------------------------------------------------------------
// Kernel C: gather-aggregate, 8-deep software pipeline (+4-deep drain).
// One wave per dst node; lane l<48 owns feature pair (2l, 2l+1).
// Output g (normalized + gat_bias) packed bf16.
// ---------------------------------------------------------------------------
__global__ __launch_bounds__(256) void k_aggregate(
    const int* __restrict__ offsets, const int* __restrict__ ssrc,
    const float* __restrict__ wsrt,
    const unsigned short* __restrict__ hb, const float* __restrict__ asrc,
    const float* __restrict__ adst, const float* __restrict__ gb,
    unsigned short* __restrict__ gbuf)
{
    const int wid  = (blockIdx.x * 256 + threadIdx.x) >> 6;
    const int lane = threadIdx.x & 63;
    if (wid >= N_NODES) return;
    const int d = wid;
    const int lp = (lane < 48) ? lane : 47;     // lanes 48-63 duplicate lane 47
    const int f0 = lp * 2;                      // features f0, f0+1 (same head)
    const int hd = f0 / HEAD_DIM;

    const int rs = offsets[d], re = offsets[d + 1];
    const int deg = re - rs;
    const int sv = (lane < deg) ? ssrc[rs + lane] : 0;   // coalesced preload

    float acc0, acc1, ds;
    {   // self-loop term (overlaps the sv load latency)
        const unsigned int hp = *(const unsigned int*)&hb[(size_t)d * DIM + f0];
        float l0 = asrc[d * HEADS + hd] + adst[d * HEADS + hd];
        l0 = (l0 > 0.f) ? l0 : SLOPE * l0;
        const float w = __expf(l0);
        acc0 = w * bf2f((unsigned short)(hp & 0xffffu));
        acc1 = w * bf2f((unsigned short)(hp >> 16));
        ds = w;
    }

#define SRCJ(j) (((j) < 64) ? __shfl(sv, (j)) : ssrc[rs + (j)])
#define ISSUE(hreg, wreg, j) do { \
        const int s_ = SRCJ(j); \
        hreg = *(const unsigned int*)&hb[(size_t)s_ * DIM + f0]; \
        wreg = wsrt[(size_t)(rs + (j)) * 4 + hd]; } while (0)
#define CONSUME(hreg, wreg) do { \
        acc0 += (wreg) * bf2f((unsigned short)((hreg) & 0xffffu)); \
        acc1 += (wreg) * bf2f((unsigned short)((hreg) >> 16)); \
        ds += (wreg); } while (0)

    int j = 0;
    if (deg >= 8) {                             // 8-deep main pipeline
        unsigned p0, p1, p2, p3, p4, p5, p6, p7;
        float    q0, q1, q2, q3, q4, q5, q6, q7;
        ISSUE(p0, q0, 0); ISSUE(p1, q1, 1); ISSUE(p2, q2, 2); ISSUE(p3, q3, 3);
        ISSUE(p4, q4, 4); ISSUE(p5, q5, 5); ISSUE(p6, q6, 6); ISSUE(p7, q7, 7);
        for (; j + 16 <= deg; j += 8) {
            CONSUME(p0, q0); ISSUE(p0, q0, j + 8);
            CONSUME(p1, q1); ISSUE(p1, q1, j + 9);
            CONSUME(p2, q2); ISSUE(p2, q2, j + 10);
            CONSUME(p3, q3); ISSUE(p3, q3, j + 11);
            CONSUME(p4, q4); ISSUE(p4, q4, j + 12);
            CONSUME(p5, q5); ISSUE(p5, q5, j + 13);
            CONSUME(p6, q6); ISSUE(p6, q6, j + 14);
            CONSUME(p7, q7); ISSUE(p7, q7, j + 15);
        }
        CONSUME(p0, q0); CONSUME(p1, q1); CONSUME(p2, q2); CONSUME(p3, q3);
        CONSUME(p4, q4); CONSUME(p5, q5); CONSUME(p6, q6); CONSUME(p7, q7);
        j += 8;
    }
    if (j + 4 <= deg) {                         // 4-deep drain
        unsigned pa, pb_, pc, pd;
        float    qa, qb, qc, qd;
        ISSUE(pa, qa, j); ISSUE(pb_, qb, j + 1); ISSUE(pc, qc, j + 2); ISSUE(pd, qd, j + 3);
        CONSUME(pa, qa); CONSUME(pb_, qb); CONSUME(pc, qc); CONSUME(pd, qd);
        j += 4;
    }
    for (; j < deg; ++j) {                      // <=3 scalar tail
        unsigned hh; float ww;
        ISSUE(hh, ww, j); CONSUME(hh, ww);
    }
#undef SRCJ
#undef ISSUE
#undef CONSUME

    if (lane < 48) {
        const float inv = 1.f / ds;             // ds > 0 (self-loop)
        const float o0 = acc0 * inv + gb[f0];
        const float o1 = acc1 * inv + gb[f0 + 1];
        *(unsigned*)&gbuf[(size_t)d * DIM + f0] = pack2bf(o0, o1);
    }
}

// ---------------------------------------------------------------------------
// Kernel D: proj = g @ PW^T via pre-transposed PWT (row-major [k][f]),
// g staged from bf16, 4-node x 8-feat register tile, + residual + LN.
// ---------------------------------------------------------------------------
__global__ __launch_bounds__(GT) void k_finalize(
    const float* __restrict__ x, const float* __restrict__ PWT,
    const float* __restrict__ pb, const float* __restrict__ lng,
    const float* __restrict__ lnb, const unsigned short* __restrict__ gbuf,
    float* __restrict__ out)
{
    __shared__ float Wl[DIM][DIM];        // PWT tile [k][f] 36.9 KB
    __shared__ float gl[TNODES][XPAD];    // 25.6 KB (g tile, reused as z tile)
    __shared__ float sred[TNODES][6], s2red[TNODES][6];
    __shared__ float mubuf[TNODES], ivbuf[TNODES];
    __shared__ float lngl[DIM], lnbl[DIM];
    const int tid = threadIdx.x;
    for (int i4 = tid; i4 < DIM * (DIM / 4); i4 += GT) {
        const int k = i4 / 24, q = i4 % 24;
        *(float4*)&Wl[k][q * 4] = *(const float4*)&PWT[k * DIM + q * 4];
    }
    if (tid < DIM) { lngl[tid] = lng[tid]; lnbl[tid] = lnb[tid]; }
    const int tf = tid % 12, tn = tid / 12;
    const int f0 = tf * 8, n0 = tn * 4;
    const float4 pba = *(const float4*)&pb[f0];
    const float4 pbb = *(const float4*)&pb[f0 + 4];

    for (int tile = blockIdx.x; tile < NTILES; tile += gridDim.x) {
        const int base = tile * TNODES;
        __syncthreads();
        for (int i8 = tid; i8 < TNODES * 12; i8 += GT) {   // 8 bf16 per iter
            const int n = i8 / 12, q = i8 % 12, gn = base + n;
            float4 lo = make_float4(0.f, 0.f, 0.f, 0.f), hi = lo;
            if (gn < N_NODES) {
                const uint4 gv = *(const uint4*)&gbuf[(size_t)gn * DIM + q * 8];
                lo = make_float4(bf2f((unsigned short)(gv.x & 0xffffu)),
                                 bf2f((unsigned short)(gv.x >> 16)),
                                 bf2f((unsigned short)(gv.y & 0xffffu)),
                                 bf2f((unsigned short)(gv.y >> 16)));
                hi = make_float4(bf2f((unsigned short)(gv.z & 0xffffu)),
                                 bf2f((unsigned short)(gv.z >> 16)),
                                 bf2f((unsigned short)(gv.w & 0xffffu)),
                                 bf2f((unsigned short)(gv.w >> 16)));
            }
            *(float4*)&gl[n][q * 8]     = lo;
            *(float4*)&gl[n][q * 8 + 4] = hi;
        }
        __syncthreads();
        float acc[4][8] = {};
        for (int k = 0; k < DIM; k += 4) {
            float4 gq[4], wa[4], wb[4];
            #pragma unroll
            for (int a = 0; a < 4; ++a) gq[a] = *(const float4*)&gl[n0 + a][k];
            #pragma unroll
            for (int j = 0; j < 4; ++j) {
                wa[j] = *(const float4*)&Wl[k + j][f0];
                wb[j] = *(const float4*)&Wl[k + j][f0 + 4];
            }
            #pragma unroll
            for (int a = 0; a < 4; ++a) {
                const float g0 = gq[a].x, g1 = gq[a].y, g2 = gq[a].z, g3 = gq[a].w;
                acc[a][0] += g0*wa[0].x + g1*wa[1].x + g2*wa[2].x + g3*wa[3].x;
                acc[a][1] += g0*wa[0].y + g1*wa[1].y + g2*wa[2].y + g3*wa[3].y;
                acc[a][2] += g0*wa[0].z + g1*wa[1].z + g2*wa[2].z + g3*wa[3].z;
                acc[a][3] += g0*wa[0].w + g1*wa[1].w + g2*wa[2].w + g3*wa[3].w;
                acc[a][4] += g0*wb[0].x + g1*wb[1].x + g2*wb[2].x + g3*wb[3].x;
                acc[a][5] += g0*wb[0].y + g1*wb[1].y + g2*wb[2].y + g3*wb[3].y;
                acc[a][6] += g0*wb[0].z + g1*wb[1].z + g2*wb[2].z + g3*wb[3].z;
                acc[a][7] += g0*wb[0].w + g1*wb[1].w + g2*wb[2].w + g3*wb[3].w;
            }
        }
        // z = x + pb + proj (registers)
        float4 za[4], zb[4];
        #pragma unroll
        for (int a = 0; a < 4; ++a) {
            const int gn = base + n0 + a;
            float4 xa = make_float4(0.f,0.f,0.f,0.f), xb = xa;
            if (gn < N_NODES) {
                xa = *(const float4*)&x[(size_t)gn * DIM + f0];
                xb = *(const float4*)&x[(size_t)gn * DIM + f0 + 4];
            }
            za[a] = make_float4(acc[a][0]+pba.x+xa.x, acc[a][1]+pba.y+xa.y,
                                acc[a][2]+pba.z+xa.z, acc[a][3]+pba.w+xa.w);
            zb[a] = make_float4(acc[a][4]+pbb.x+xb.x, acc[a][5]+pbb.y+xb.y,
                                acc[a][6]+pbb.z+xb.z, acc[a][7]+pbb.w+xb.w);
        }
        __syncthreads();   // gl (g) reads done -> reuse as z tile
        #pragma unroll
        for (int a = 0; a < 4; ++a) {
            *(float4*)&gl[n0 + a][f0]     = za[a];
            *(float4*)&gl[n0 + a][f0 + 4] = zb[a];
        }
        __syncthreads();
        for (int i = tid; i < TNODES * 6; i += GT) {   // partials: 6/node x 16
            const int n = i / 6, jj = i % 6;
            float s = 0.f, s2 = 0.f;
            #pragma unroll
            for (int c = 0; c < 16; ++c) {
                const float v = gl[n][jj * 16 + c];
                s += v; s2 += v * v;
            }
            sred[n][jj] = s; s2red[n][jj] = s2;
        }
        __syncthreads();
        if (tid < TNODES) {
            float s = 0.f, s2 = 0.f;
            #pragma unroll
            for (int jj = 0; jj < 6; ++jj) { s += sred[tid][jj]; s2 += s2red[tid][jj]; }
            const float mu = s * (1.f / DIM);
            const float var = s2 * (1.f / DIM) - mu * mu;
            mubuf[tid] = mu;
            ivbuf[tid] = rsqrtf(var + LN_EPS);
        }
        __syncthreads();
        for (int i = tid; i < TNODES * 24; i += GT) {
            const int n = i / 24, c = i % 24, gn = base + n;
            if (gn < N_NODES) {
                const float4 v = *(const float4*)&gl[n][c * 4];
                const float mu = mubuf[n], iv = ivbuf[n];
                float4 o;
                o.x = lngl[c*4+0] * (v.x - mu) * iv + lnbl[c*4+0];
                o.y = lngl[c*4+1] * (v.y - mu) * iv + lnbl[c*4+1];
                o.z = lngl[c*4+2] * (v.z - mu) * iv + lnbl[c*4+2];
                o.w = lngl[c*4+3] * (v.w - mu) * iv + lnbl[c*4+3];
                *(float4*)&out[(size_t)gn * DIM + c * 4] = o;
            }
        }
    }
}

// ---------------------------------------------------------------------------
extern "C" void kernel_launch(void* const* d_in, const int* in_sizes, int n_in,
                              void* d_out, int out_size, void* d_ws, size_t ws_size,
                              hipStream_t stream)
{
    const float* x    = (const float*)d_in[0];
    const int*   ei   = (const int*)d_in[1];     // [2, E] int32 (harness-converted)
    const float* W    = (const float*)d_in[2];
    const float* attS = (const float*)d_in[3];
    const float* attD = (const float*)d_in[4];
    const float* gb   = (const float*)d_in[5];
    const float* PW   = (const float*)d_in[6];
    const float* pb   = (const float*)d_in[7];
    const float* lng  = (const float*)d_in[8];
    const float* lnb  = (const float*)d_in[9];
    float* out = (float*)d_out;

    char* ws = (char*)d_ws;
    float* wsrt    = (float*)ws;                                  // E*4 f32 (12.8 MB)
    float* asrc    = wsrt + (size_t)N_EDGES * 4;                  // N*4
    float* adst    = asrc + N_NODES * HEADS;                      // N*4
    unsigned short* hb   = (unsigned short*)(adst + N_NODES * HEADS); // N*96 bf16
    unsigned short* gbuf = hb + (size_t)N_NODES * DIM;            // N*96 bf16
    float* pwt     = (float*)(gbuf + (size_t)N_NODES * DIM);      // 96*96 f32
    int*   counts  = (int*)(pwt + DIM * DIM);                     // N
    int*   offsets = counts + N_NODES;                            // N+1
    int*   cursor  = offsets + N_NODES + 1;                       // N
    int*   bsum    = cursor + N_NODES;                            // SCAN_NB
    int*   ssrc    = bsum + SCAN_NB;                              // E

    k_prep        <<<(N_NODES + 255) / 256, 256, 0, stream>>>(PW, pwt, counts);
    k_hist        <<<(N_EDGES + 255) / 256, 256, 0, stream>>>(ei, counts);
    k_scan_partial<<<SCAN_NB, SCAN_BLK, 0, stream>>>(counts, bsum);
    k_scan_final  <<<SCAN_NB, SCAN_BLK, 0, stream>>>(counts, bsum, offsets, cursor);
    k_transform   <<<NTILES, GT, 0, stream>>>(x, W, attS, attD, hb, asrc, adst);
    k_scatter_w   <<<(N_EDGES + 255) / 256, 256, 0, stream>>>(ei, cursor, asrc, adst, ssrc, wsrt);
    k_aggregate   <<<(N_NODES * 64 + 255) / 256, 256, 0, stream>>>(offsets, ssrc, wsrt, hb, asrc, adst, gb, gbuf);
    k_finalize    <<<NTILES, GT, 0, stream>>>(x, pwt, pb, lng, lnb, gbuf, out);
}